// Round 1
// baseline (2292.228 us; speedup 1.0000x reference)
//
#include <hip/hip_runtime.h>
#include <math.h>

#define H_ 256
#define W_ 320
#define C_ 28
#define NPIX (2 * H_ * W_)          // 163840
#define HWC (H_ * W_ * C_)          // 2293760 elems per batch
#define PI_D 3.14159265358979323846

__device__ __forceinline__ float gelu_f(float x) {
    return 0.5f * x * (1.0f + erff(x * 0.7071067811865476f));
}

// ---------------------------------------------------------------------------
// DCT basis matrices + analytic inverse (torch_dct DCT-II, norm=None)
// D[k][n]  = 2*cos(pi*(2n+1)k/(2N));  DI[n][k] = (k==0 ? 1/(2N) : cos(.)/N)
// ---------------------------------------------------------------------------
__global__ void gen_mats(float* __restrict__ dh, float* __restrict__ dw,
                         float* __restrict__ dih, float* __restrict__ diw) {
    int i = blockIdx.x * 256 + threadIdx.x;
    if (i < 256 * 256) {
        int k = i >> 8, n = i & 255;
        double c = cos(PI_D * (2.0 * n + 1.0) * k / 512.0);
        dh[k * 256 + n] = (float)(2.0 * c);
        dih[n * 256 + k] = (float)(k == 0 ? (1.0 / 512.0) : c / 256.0);
    }
    if (i < 320 * 320) {
        int k = i / 320, n = i - k * 320;
        double c = cos(PI_D * (2.0 * n + 1.0) * k / 640.0);
        dw[k * 320 + n] = (float)(2.0 * c);
        diw[n * 320 + k] = (float)(k == 0 ? (1.0 / 640.0) : c / 320.0);
    }
}

// G[h][c][c'] = sum_d wq[c, h*28+d] * wkv[c', h*28+d] * 28^-0.5   (local attn)
__global__ void gen_locG(const float* __restrict__ wq, const float* __restrict__ wkv,
                         float* __restrict__ G) {
    int i = blockIdx.x * 256 + threadIdx.x;  // 8*28*28 = 6272
    if (i < 6272) {
        int h = i / 784, r = i - h * 784;
        int c = r / 28, cp = r - c * 28;
        float s = 0.f;
        #pragma unroll
        for (int d = 0; d < 28; ++d)
            s += wq[c * 224 + h * 28 + d] * wkv[cp * 448 + h * 28 + d];
        G[i] = s * 0.18898223650461363f;  // 28^-0.5
    }
}

// ---------------------------------------------------------------------------
// Generic strided matrix apply: out[m, c] = sum_k mat[m,k] * in[k, c]  (c=28)
// Used for both DCT passes (fwd & inverse). One block per batch item.
// ---------------------------------------------------------------------------
__global__ void dct_apply(const float* __restrict__ mat, const float* __restrict__ in,
                          float* __restrict__ out, int M, int Kd, int inner_n,
                          int stride_i_in, int kstride_in,
                          int stride_i_out, int mstride_out) {
    extern __shared__ float s_in[];  // [Kd][28]
    int bidx = blockIdx.x;
    int o = bidx / inner_n;
    int ii = bidx - o * inner_n;
    const float* bin = in + (size_t)o * HWC + (size_t)ii * stride_i_in;
    float* bout = out + (size_t)o * HWC + (size_t)ii * stride_i_out;
    int tot = Kd * C_;
    for (int e = threadIdx.x; e < tot; e += blockDim.x) {
        int k = e / C_;
        int c = e - k * C_;
        s_in[e] = bin[k * kstride_in + c];
    }
    __syncthreads();
    int m = threadIdx.x;
    if (m < M) {
        float4 acc[7];
        #pragma unroll
        for (int q = 0; q < 7; ++q) acc[q] = make_float4(0.f, 0.f, 0.f, 0.f);
        const float* mr = mat + (size_t)m * Kd;
        for (int k = 0; k < Kd; ++k) {
            float d = mr[k];
            const float4* row = (const float4*)(s_in + k * C_);
            #pragma unroll
            for (int q = 0; q < 7; ++q) {
                float4 v = row[q];
                acc[q].x += d * v.x; acc[q].y += d * v.y;
                acc[q].z += d * v.z; acc[q].w += d * v.w;
            }
        }
        float4* orow = (float4*)(bout + (size_t)m * mstride_out);
        #pragma unroll
        for (int q = 0; q < 7; ++q) orow[q] = acc[q];
    }
}

// ---------------------------------------------------------------------------
// Spectral DCT-domain attention: one block per (b, 8x8 DCT patch)
// attention over d=28 (per-head channel), features m=64, q/k l2-normalized
// ---------------------------------------------------------------------------
__global__ __launch_bounds__(256) void spec_attn(
    const float* __restrict__ xdct, const float* __restrict__ wq,
    const float* __restrict__ wk, const float* __restrict__ wv,
    const float* __restrict__ rescale, const float* __restrict__ pw,
    const float* __restrict__ pb, float* __restrict__ xlow) {
    __shared__ float s_xt[64][29];
    __shared__ float s_q[64][29];
    __shared__ float s_k[64][29];
    __shared__ float s_v[64][29];
    __shared__ float s_acc[64][29];
    __shared__ float s_wq[28][29];
    __shared__ float s_wk[28][29];
    __shared__ float s_wv[28][29];
    __shared__ float s_pw[28][29];
    __shared__ float s_p[28][29];
    __shared__ float s_x0[28][64];
    __shared__ float s_qn[28];
    __shared__ float s_kn[28];
    int t = threadIdx.x;
    int blk = blockIdx.x;
    int b = blk / 1280;
    int r = blk - b * 1280;
    int bh = r / 40;
    int bw = r - bh * 40;
    const float* base = xdct + ((size_t)((b * 256 + bh * 8) * 320 + bw * 8)) * 28;
    for (int e = t; e < 1792; e += 256) {
        int m = e / 28, c = e - m * 28;
        int kp = m >> 3, lp = m & 7;
        s_xt[m][c] = base[(kp * 320 + lp) * 28 + c];
        s_acc[m][c] = pb[c];
    }
    for (int h = 0; h < 8; ++h) {
        float resc = rescale[h];
        __syncthreads();
        for (int e = t; e < 784; e += 256) {
            int c = e / 28, d = e - c * 28;
            s_wq[c][d] = wq[c * 224 + h * 28 + d];
            s_wk[c][d] = wk[c * 224 + h * 28 + d];
            s_wv[c][d] = wv[c * 224 + h * 28 + d];
            s_pw[c][d] = pw[(h * 28 + c) * 28 + d];
        }
        __syncthreads();
        // Q,K,V [64,28]
        for (int e = t; e < 1792; e += 256) {
            int m = e / 28, d = e - m * 28;
            float aq = 0.f, ak = 0.f, av = 0.f;
            #pragma unroll
            for (int c = 0; c < 28; ++c) {
                float xv = s_xt[m][c];
                aq += xv * s_wq[c][d];
                ak += xv * s_wk[c][d];
                av += xv * s_wv[c][d];
            }
            s_q[m][d] = aq; s_k[m][d] = ak; s_v[m][d] = av;
        }
        __syncthreads();
        // column norms over m (l2norm over mm axis)
        if (t < 28) {
            float s = 0.f;
            #pragma unroll 8
            for (int m2 = 0; m2 < 64; ++m2) { float v = s_q[m2][t]; s += v * v; }
            s_qn[t] = fmaxf(sqrtf(s), 1e-12f);
        } else if (t < 56) {
            int col = t - 28;
            float s = 0.f;
            #pragma unroll 8
            for (int m2 = 0; m2 < 64; ++m2) { float v = s_k[m2][col]; s += v * v; }
            s_kn[col] = fmaxf(sqrtf(s), 1e-12f);
        }
        __syncthreads();
        // attn[d][e] = resc * <q_d, k_e> / (|q_d||k_e|)
        for (int e = t; e < 784; e += 256) {
            int d = e / 28, ee = e - d * 28;
            float s = 0.f;
            #pragma unroll 8
            for (int m2 = 0; m2 < 64; ++m2) s += s_q[m2][d] * s_k[m2][ee];
            s_p[d][ee] = s * resc / (s_qn[d] * s_kn[ee]);
        }
        __syncthreads();
        // softmax rows over e (28)
        if (t < 28) {
            float mx = -1e30f;
            #pragma unroll
            for (int e2 = 0; e2 < 28; ++e2) mx = fmaxf(mx, s_p[t][e2]);
            float sum = 0.f;
            #pragma unroll
            for (int e2 = 0; e2 < 28; ++e2) {
                float ex = expf(s_p[t][e2] - mx);
                s_p[t][e2] = ex; sum += ex;
            }
            float inv = 1.0f / sum;
            #pragma unroll
            for (int e2 = 0; e2 < 28; ++e2) s_p[t][e2] *= inv;
        }
        __syncthreads();
        // x0[d][m] = sum_e p[d][e] * V[m][e]
        for (int e = t; e < 1792; e += 256) {
            int d = e >> 6, m2 = e & 63;
            float s = 0.f;
            #pragma unroll
            for (int ee = 0; ee < 28; ++ee) s += s_p[d][ee] * s_v[m2][ee];
            s_x0[d][m2] = s;
        }
        __syncthreads();
        // acc[m][co] += sum_d x0[d][m] * pw[d][co]
        for (int e = t; e < 1792; e += 256) {
            int m2 = e / 28, co = e - m2 * 28;
            float s = 0.f;
            #pragma unroll
            for (int d = 0; d < 28; ++d) s += s_x0[d][m2] * s_pw[d][co];
            s_acc[m2][co] += s;
        }
    }
    __syncthreads();
    float* outp = xlow + ((size_t)((b * 256 + bh * 8) * 320 + bw * 8)) * 28;
    for (int e = t; e < 1792; e += 256) {
        int m = e / 28, c = e - m * 28;
        int kp = m >> 3, lp = m & 7;
        outp[(kp * 320 + lp) * 28 + c] = s_acc[m][c];
    }
}

// ---------------------------------------------------------------------------
// y1 = gelu(pointwise-conv(x_dct)), per-pixel 28x28 matvec, LDS-staged
// ---------------------------------------------------------------------------
__global__ __launch_bounds__(256) void hf_pw1(const float* __restrict__ xdct,
                                              const float* __restrict__ w,
                                              float* __restrict__ y1) {
    __shared__ float s_w[28][29];
    __shared__ float s_x[256][29];
    int t = threadIdx.x;
    for (int e = t; e < 784; e += 256) s_w[e / 28][e % 28] = w[e];
    size_t p0 = (size_t)blockIdx.x * 256;
    const float* src = xdct + p0 * 28;
    for (int e = t; e < 7168; e += 256) {
        int p = e / 28, c = e - p * 28;
        s_x[p][c] = src[e];
    }
    __syncthreads();
    float o[28];
    #pragma unroll
    for (int oo = 0; oo < 28; ++oo) {
        float a = 0.f;
        #pragma unroll
        for (int c = 0; c < 28; ++c) a += s_w[oo][c] * s_x[t][c];
        o[oo] = gelu_f(a);
    }
    __syncthreads();
    #pragma unroll
    for (int oo = 0; oo < 28; ++oo) s_x[t][oo] = o[oo];
    __syncthreads();
    float* dst = y1 + p0 * 28;
    for (int e = t; e < 7168; e += 256) {
        int p = e / 28, c = e - p * 28;
        dst[e] = s_x[p][c];
    }
}

// ---------------------------------------------------------------------------
// Depthwise 3x3 + gelu + residual + pointwise2 + gelu + residual + coef blend
// x_out = coef*x_low + (1-coef)*x_high + x_dct
// ---------------------------------------------------------------------------
__global__ __launch_bounds__(256) void hf_combine(
    const float* __restrict__ y1, const float* __restrict__ xdct,
    const float* __restrict__ xlow, const float* __restrict__ dww,
    const float* __restrict__ pw2, const float* __restrict__ coef,
    float* __restrict__ xout) {
    __shared__ float s_dw[252];
    __shared__ float s_pw[28][29];
    int t = threadIdx.x;
    for (int e = t; e < 252; e += 256) s_dw[e] = dww[e];
    for (int e = t; e < 784; e += 256) s_pw[e / 28][e % 28] = pw2[e];
    __syncthreads();
    int pix = blockIdx.x * 256 + t;
    int b = pix / 81920;
    int rem = pix - b * 81920;
    int y = rem / 320;
    int xx = rem - y * 320;
    float conv[28];
    #pragma unroll
    for (int c = 0; c < 28; ++c) conv[c] = 0.f;
    for (int dy = 0; dy < 3; ++dy) {
        int yy = y + dy - 1;
        if (yy < 0 || yy >= 256) continue;
        for (int dx = 0; dx < 3; ++dx) {
            int xq = xx + dx - 1;
            if (xq < 0 || xq >= 320) continue;
            const float* rp = y1 + ((size_t)(b * 256 + yy) * 320 + xq) * 28;
            #pragma unroll
            for (int c = 0; c < 28; ++c) conv[c] += s_dw[c * 9 + dy * 3 + dx] * rp[c];
        }
    }
    const float* xd = xdct + (size_t)pix * 28;
    const float* xl = xlow + (size_t)pix * 28;
    float xdr[28], xcv[28];
    #pragma unroll
    for (int c = 0; c < 28; ++c) {
        xdr[c] = xd[c];
        xcv[c] = gelu_f(conv[c]) + xdr[c];
    }
    float cf = coef[rem];
    float omc = 1.0f - cf;
    float* xo = xout + (size_t)pix * 28;
    #pragma unroll
    for (int oo = 0; oo < 28; ++oo) {
        float a = 0.f;
        #pragma unroll
        for (int c = 0; c < 28; ++c) a += s_pw[oo][c] * xcv[c];
        float xh = gelu_f(a) + xcv[oo];
        xo[oo] = cf * xl[oo] + omc * xh + xdr[oo];
    }
}

// ---------------------------------------------------------------------------
// Windowed local attention: one block per 8x8 window.
// sim = (xw @ G) @ xw^T + pos, with G = Wq Wk^T * 28^-0.5 precomputed.
// ---------------------------------------------------------------------------
__global__ __launch_bounds__(256) void local_attn(
    const float* __restrict__ x, const float* __restrict__ G,
    const float* __restrict__ wkv, const float* __restrict__ pos,
    const float* __restrict__ pw, const float* __restrict__ pb,
    float* __restrict__ outloc) {
    __shared__ float s_xw[64][29];
    __shared__ float s_t1[64][29];
    __shared__ float s_v[64][29];
    __shared__ float s_ol[64][29];
    __shared__ float s_acc[64][29];
    __shared__ float s_G[28][29];
    __shared__ float s_wv[28][29];
    __shared__ float s_pw[28][29];
    __shared__ float s_sim[64][65];
    int t = threadIdx.x;
    int blk = blockIdx.x;
    int b = blk / 1280;
    int r = blk - b * 1280;
    int wh = r / 40;
    int wwi = r - wh * 40;
    const float* base = x + ((size_t)((b * 256 + wh * 8) * 320 + wwi * 8)) * 28;
    for (int e = t; e < 1792; e += 256) {
        int i = e / 28, c = e - i * 28;
        int p = i >> 3, q = i & 7;
        s_xw[i][c] = base[(p * 320 + q) * 28 + c];
        s_acc[i][c] = pb[c];
    }
    for (int h = 0; h < 8; ++h) {
        __syncthreads();
        for (int e = t; e < 784; e += 256) {
            int c = e / 28, d = e - c * 28;
            s_G[c][d] = G[h * 784 + e];
            s_wv[c][d] = wkv[c * 448 + 224 + h * 28 + d];
            s_pw[c][d] = pw[(h * 28 + c) * 28 + d];
        }
        __syncthreads();
        // t1 = xw @ G  and  V = xw @ Wv
        for (int e = t; e < 1792; e += 256) {
            int i = e / 28, d = e - i * 28;
            float a1 = 0.f, a2 = 0.f;
            #pragma unroll
            for (int c = 0; c < 28; ++c) {
                float xv = s_xw[i][c];
                a1 += xv * s_G[c][d];
                a2 += xv * s_wv[c][d];
            }
            s_t1[i][d] = a1;
            s_v[i][d] = a2;
        }
        __syncthreads();
        const float* ph = pos + h * 4096;
        for (int e = t; e < 4096; e += 256) {
            int i = e >> 6, j = e & 63;
            float s = 0.f;
            #pragma unroll
            for (int c = 0; c < 28; ++c) s += s_t1[i][c] * s_xw[j][c];
            s_sim[i][j] = s + ph[e];
        }
        __syncthreads();
        if (t < 64) {
            float mx = -1e30f;
            #pragma unroll 8
            for (int j = 0; j < 64; ++j) mx = fmaxf(mx, s_sim[t][j]);
            float sum = 0.f;
            for (int j = 0; j < 64; ++j) {
                float ex = expf(s_sim[t][j] - mx);
                s_sim[t][j] = ex; sum += ex;
            }
            float inv = 1.0f / sum;
            for (int j = 0; j < 64; ++j) s_sim[t][j] *= inv;
        }
        __syncthreads();
        for (int e = t; e < 1792; e += 256) {
            int i = e / 28, d = e - i * 28;
            float s = 0.f;
            #pragma unroll 8
            for (int j = 0; j < 64; ++j) s += s_sim[i][j] * s_v[j][d];
            s_ol[i][d] = s;
        }
        __syncthreads();
        for (int e = t; e < 1792; e += 256) {
            int i = e / 28, co = e - i * 28;
            float s = 0.f;
            #pragma unroll
            for (int d = 0; d < 28; ++d) s += s_ol[i][d] * s_pw[d][co];
            s_acc[i][co] += s;
        }
    }
    __syncthreads();
    float* outp = outloc + ((size_t)((b * 256 + wh * 8) * 320 + wwi * 8)) * 28;
    for (int e = t; e < 1792; e += 256) {
        int i = e / 28, c = e - i * 28;
        int p = i >> 3, q = i & 7;
        outp[(p * 320 + q) * 28 + c] = s_acc[i][c];
    }
}

// ---------------------------------------------------------------------------
// Fusion: out = fus_w[:, :28] @ out_fd + fus_w[:, 28:] @ out_local + fus_b
// ---------------------------------------------------------------------------
__global__ __launch_bounds__(256) void fuse_k(
    const float* __restrict__ fd, const float* __restrict__ loc,
    const float* __restrict__ w, const float* __restrict__ bias,
    float* __restrict__ out) {
    __shared__ float s_w[28][57];
    __shared__ float s_b[28];
    int t = threadIdx.x;
    for (int e = t; e < 28 * 56; e += 256) s_w[e / 56][e % 56] = w[e];
    if (t < 28) s_b[t] = bias[t];
    __syncthreads();
    size_t pix = (size_t)blockIdx.x * 256 + t;
    const float* f = fd + pix * 28;
    const float* l = loc + pix * 28;
    float fr[28], lr[28];
    #pragma unroll
    for (int c = 0; c < 28; ++c) { fr[c] = f[c]; lr[c] = l[c]; }
    float* o = out + pix * 28;
    #pragma unroll
    for (int oo = 0; oo < 28; ++oo) {
        float a = s_b[oo];
        #pragma unroll
        for (int c = 0; c < 28; ++c) a += s_w[oo][c] * fr[c] + s_w[oo][28 + c] * lr[c];
        o[oo] = a;
    }
}

extern "C" void kernel_launch(void* const* d_in, const int* in_sizes, int n_in,
                              void* d_out, int out_size, void* d_ws, size_t ws_size,
                              hipStream_t stream) {
    const float* x         = (const float*)d_in[0];
    const float* spec_wq   = (const float*)d_in[1];
    const float* spec_wk   = (const float*)d_in[2];
    const float* spec_wv   = (const float*)d_in[3];
    const float* spec_resc = (const float*)d_in[4];
    const float* spec_pw   = (const float*)d_in[5];
    const float* spec_pb   = (const float*)d_in[6];
    const float* hf1_pw_w  = (const float*)d_in[7];
    const float* hf1_dw_w  = (const float*)d_in[8];
    const float* hf2_pw_w  = (const float*)d_in[9];
    const float* coef_emb  = (const float*)d_in[10];
    const float* loc_wq    = (const float*)d_in[11];
    const float* loc_wkv   = (const float*)d_in[12];
    const float* loc_pos   = (const float*)d_in[13];
    const float* loc_pw    = (const float*)d_in[14];
    const float* loc_pb    = (const float*)d_in[15];
    const float* fus_w     = (const float*)d_in[16];
    const float* fus_b     = (const float*)d_in[17];

    float* ws = (float*)d_ws;
    float* mDH  = ws;                       // 65536
    float* mDW  = mDH + 65536;              // 102400
    float* mDIH = mDW + 102400;             // 65536
    float* mDIW = mDIH + 65536;             // 102400
    float* locG = mDIW + 102400;            // 6272
    float* bufA = locG + 6272;              // 2*HWC each
    float* bufB = bufA + 2 * HWC;
    float* bufC = bufB + 2 * HWC;
    float* bufD = bufC + 2 * HWC;

    gen_mats<<<400, 256, 0, stream>>>(mDH, mDW, mDIH, mDIW);
    gen_locG<<<25, 256, 0, stream>>>(loc_wq, loc_wkv, locG);

    // forward DCT: pass1 over H (batch = b,w), pass2 over W (batch = b,k)
    dct_apply<<<640, 256, 256 * 28 * 4, stream>>>(mDH, x, bufA,
        256, 256, 320, /*stride_i_in*/28, /*kstride_in*/8960, /*stride_i_out*/28, /*mstride_out*/8960);
    dct_apply<<<512, 320, 320 * 28 * 4, stream>>>(mDW, bufA, bufB,
        320, 320, 256, 8960, 28, 8960, 28);

    // spectral attention -> x_low (bufC)
    spec_attn<<<2560, 256, 0, stream>>>(bufB, spec_wq, spec_wk, spec_wv,
                                        spec_resc, spec_pw, spec_pb, bufC);
    // high-frequency path
    hf_pw1<<<640, 256, 0, stream>>>(bufB, hf1_pw_w, bufA);
    hf_combine<<<640, 256, 0, stream>>>(bufA, bufB, bufC, hf1_dw_w, hf2_pw_w,
                                        coef_emb, bufD);
    // inverse DCT: x_out (bufD) -> out_fd (bufC)
    dct_apply<<<640, 256, 256 * 28 * 4, stream>>>(mDIH, bufD, bufA,
        256, 256, 320, 28, 8960, 28, 8960);
    dct_apply<<<512, 320, 320 * 28 * 4, stream>>>(mDIW, bufA, bufC,
        320, 320, 256, 8960, 28, 8960, 28);

    // local windowed attention -> bufB
    local_attn<<<2560, 256, 0, stream>>>(x, locG, loc_wkv, loc_pos,
                                         loc_pw, loc_pb, bufB);

    // fusion -> output
    fuse_k<<<640, 256, 0, stream>>>(bufC, bufB, fus_w, fus_b, (float*)d_out);
}